// Round 3
// baseline (5388.818 us; speedup 1.0000x reference)
//
#include <hip/hip_runtime.h>

typedef unsigned short u16;
typedef short bhalf8 __attribute__((ext_vector_type(8)));
typedef float floatx4 __attribute__((ext_vector_type(4)));

// B=4096, DX=128, DD=128, N=64, ND=16, T=81, DH=1024, L=3, DT=0.02, EPS=1e-5

__device__ __forceinline__ float b2f(u16 h) {
  unsigned int u = ((unsigned int)h) << 16; float f; __builtin_memcpy(&f, &u, 4); return f;
}
__device__ __forceinline__ u16 f2b(float f) {
  unsigned int u; __builtin_memcpy(&u, &f, 4);
  u = u + 0x7fffu + ((u >> 16) & 1u);           // RNE bf16
  return (u16)(u >> 16);
}
__device__ __forceinline__ float tanh_fast(float x) {
  float cx = fminf(fmaxf(x, -15.f), 15.f);
  float e = __expf(2.f * cx);
  return __fdividef(e - 1.f, e + 1.f);
}
__device__ __forceinline__ void gll16(const void* g, void* l) {
  __builtin_amdgcn_global_load_lds(
      (const __attribute__((address_space(1))) unsigned int*)g,
      (__attribute__((address_space(3))) unsigned int*)l, 16, 0, 0);
}

// ---------------- x stats: per (d, t) column over batch, t in [0,80) ----------------
__global__ void xstats_partial(const float* __restrict__ x, float* __restrict__ ps, float* __restrict__ pq) {
  int p = blockIdx.x * 256 + threadIdx.x;      // 0..10239  (d*80+t)
  int bc = blockIdx.y;                          // 0..15
  int d = p / 80, t = p % 80;
  const float* xp = x + (size_t)d * 81 + t;
  float s = 0.f, q = 0.f;
  int b0 = bc * 256;
  for (int b = b0; b < b0 + 256; ++b) {
    float v = xp[(size_t)b * 10368];
    s += v; q += v * v;
  }
  ps[(size_t)bc * 10240 + p] = s;
  pq[(size_t)bc * 10240 + p] = q;
}

__global__ void xstats_final(const float* __restrict__ ps, const float* __restrict__ pq,
                             float* __restrict__ meanx, float* __restrict__ rstdx) {
  int p = blockIdx.x * 256 + threadIdx.x;
  float s = 0.f, q = 0.f;
  for (int c = 0; c < 16; ++c) { s += ps[(size_t)c * 10240 + p]; q += pq[(size_t)c * 10240 + p]; }
  float m = s * (1.0f / 4096.0f);
  float v = q * (1.0f / 4096.0f) - m * m;
  meanx[p] = m;
  rstdx[p] = rsqrtf(v + 1e-5f);
}

// ------- build normalized input [G][4096][320] bf16 for steps c0..c0+G-1, + xs -------
__global__ void build_inpt(const float* __restrict__ x, const float* __restrict__ meanx,
                           const float* __restrict__ rstdx, const float* __restrict__ g,
                           const float* __restrict__ bb, u16* __restrict__ inpt,
                           float* __restrict__ xs, int c0, int G) {
  __shared__ float xl[128 * 33];                // window <=32 cols, padded stride 33
  int b = blockIdx.x, tid = threadIdx.x;
  int W = G + 16;                               // columns needed: [c0, c0+G+16)
  const float* xb = x + (size_t)b * 10368;
  for (int j = tid; j < 128 * W; j += 256) {
    int d = j / W, t = j % W;
    xl[d * 33 + t] = xb[(size_t)d * 81 + c0 + t];
  }
  __syncthreads();
  int lane = tid & 63, wid = tid >> 6;
  for (int i = wid; i < G; i += 4) {
    float s = xl[lane * 33 + i + 16] + xl[(lane + 64) * 33 + i + 16];
#pragma unroll
    for (int off = 32; off > 0; off >>= 1) s += __shfl_xor(s, off);
    if (lane == 0) xs[(size_t)(c0 + i) * 4096 + b] = 0.01f * s;
  }
  for (int i = 0; i < G; ++i) {
    u16* row = inpt + ((size_t)i * 4096 + b) * 320;
    int tt = c0 + i + 16, td = c0 + i;
    for (int col = tid; col < 320; col += 256) {
      float val;
      if (col < 128) {
        int d = col;
        val = (xl[d * 33 + i + 16] - meanx[d * 80 + tt]) * rstdx[d * 80 + tt] * g[col] + bb[col];
      } else if (col < 256) {
        int d = col - 128;
        val = (xl[d * 33 + i] - meanx[d * 80 + td]) * rstdx[d * 80 + td] * g[col] + bb[col];
      } else if (col == 256) {
        val = bb[256];           // constant column: (x-mean)=0 -> bias only
      } else {
        val = 0.f;               // K padding 257->320
      }
      row[col] = f2b(val);
    }
  }
}

// --------------- W_in transpose to [1024][320] bf16 (zero-padded K) ------------------
__global__ void transpose_win(const float* __restrict__ W, u16* __restrict__ Wt) {
  int id = blockIdx.x * 256 + threadIdx.x;      // over 1024*320
  int n = id / 320, k = id % 320;
  float v = (k < 257) ? W[(size_t)k * 1024 + n] : 0.f;
  Wt[id] = f2b(v);
}

// ------ stats final: sum 64 per-64-row partials -> a (scale), c (shift) --------------
__global__ void stats_final_S(const float* __restrict__ ps, const float* __restrict__ pq,
                              const float* __restrict__ g, const float* __restrict__ bb,
                              float* __restrict__ a_buf, float* __restrict__ c_buf, int GK) {
  int id = blockIdx.x * 256 + threadIdx.x;      // over G*1024
  int col = id & 1023;
  float s = 0.f, q = 0.f;
  for (int rc = 0; rc < 64; ++rc) { s += ps[(size_t)rc * GK + id]; q += pq[(size_t)rc * GK + id]; }
  float m = s * (1.0f / 4096.0f);
  float v = q * (1.0f / 4096.0f) - m * m;
  float a = g[col] * rsqrtf(v + 1e-5f);
  a_buf[id] = a;
  c_buf[id] = bb[col] - m * a;
}

// --------- W' materialization: Wt[s][n][k] = a[s][k] * W[k][n], bf16, K=1024 ---------
__global__ void scaleW(const float* __restrict__ W, const float* __restrict__ a_buf,
                       u16* __restrict__ Wt, int N, int G) {
  __shared__ float T[64][65];
  __shared__ float aa[64];
  int n0 = blockIdx.x * 64, k0 = blockIdx.y * 64;
  int tid = threadIdx.x;
  int tn = tid & 63, t4 = tid >> 6;
  for (int it = 0; it < 16; ++it) {
    int k = it * 4 + t4;
    T[tn][k] = W[(size_t)(k0 + k) * N + n0 + tn];
  }
  __syncthreads();
  int wk = tid & 63, w4 = tid >> 6;
  for (int s = 0; s < G; ++s) {
    if (tid < 64) aa[tid] = a_buf[(size_t)s * 1024 + k0 + tid];
    __syncthreads();
    u16* out = Wt + ((size_t)s * N + n0) * 1024 + k0;
    for (int it = 0; it < 16; ++it) {
      int n = it * 4 + w4;
      out[(size_t)n * 1024 + wk] = f2b(T[n][wk] * aa[wk]);
    }
    __syncthreads();
  }
}

// --------- bias fold: bias2[s][n] = b0[n] + sum_k c[s][k]*W[k][n] --------------------
__global__ void biasfold(const float* __restrict__ W, const float* __restrict__ c_buf,
                         const float* __restrict__ b0, float* __restrict__ bias2, int N) {
  __shared__ float cl[1024];
  int s = blockIdx.y;
  int n = blockIdx.x * blockDim.x + threadIdx.x;
  for (int j = threadIdx.x; j < 1024; j += blockDim.x) cl[j] = c_buf[(size_t)s * 1024 + j];
  __syncthreads();
  if (n < N) {
    float acc = b0[n];
#pragma unroll 4
    for (int k = 0; k < 1024; ++k) acc += cl[k] * W[(size_t)k * N + n];
    bias2[(size_t)s * N + n] = acc;
  }
}

// ----------------------------- the GEMM (m97-style) ----------------------------------
// A: [G*4096][K] bf16.  Bt: per-(local)step [N][K] bf16 (pre-transposed/scaled).
// C: [G*4096][N];  flags: 1 = tanh + bf16 out, 2 = f32 out (no tanh),
//                  4 = fuse column stats (sum, sum-sq over rows) into ps/pq partials.
// Stats path is barrier-free: each wm-wave-group shfl-reduces its 64 rows and q==0
// lanes store a per-group partial (64 partials total). A __syncthreads here would
// force vmcnt(0) drain of the scattered C-stores (measured +38us in round 2).
// XCD-aware bijective block swizzle (T1): consecutive work-ids (which share A/B
// panels) land on the SAME XCD so the per-XCD 4MB L2 captures panel reuse.
__global__ __launch_bounds__(256, 2)
void gemm_bt(const u16* __restrict__ A, const u16* __restrict__ Bt,
             const float* __restrict__ bias, void* __restrict__ Cv,
             int K, int N, long long sB, int sBias, int flags,
             float* __restrict__ ps, float* __restrict__ pq) {
  __shared__ alignas(16) u16 As[128 * 64];
  __shared__ alignas(16) u16 Bs[128 * 64];
  const int tid = threadIdx.x;

  // ---- bijective XCD swizzle over the full 3D grid (x fastest in work-id) ----
  const int gx = gridDim.x;
  const int gxy = gx * gridDim.y;
  const int nwg = gxy * gridDim.z;
  const int orig = blockIdx.z * gxy + blockIdx.y * gx + blockIdx.x;
  const int qq = nwg >> 3, r8 = nwg & 7;
  const int xcd = orig & 7, off8 = orig >> 3;
  const int wg = (xcd < r8 ? xcd * (qq + 1) : r8 * (qq + 1) + (xcd - r8) * qq) + off8;
  const int step = wg / gxy;
  const int wrem = wg - step * gxy;
  const int mb = wrem / gx;
  const int m0 = mb * 128;
  const int n0 = (wrem % gx) * 128;

  const size_t row0 = (size_t)step * 4096 + m0;
  const u16* Ab = A + row0 * (size_t)K;
  const u16* Bb = Bt + (size_t)step * (size_t)sB + (size_t)n0 * (size_t)K;

  // staging pointers (16B chunks; xor-swizzle chunks within each 128B row)
  const u16* ag[4]; const u16* bg[4]; u16* al[4]; u16* bl[4];
#pragma unroll
  for (int j = 0; j < 4; ++j) {
    int ci = j * 256 + tid;
    int row = ci >> 3, cc = ci & 7;
    int gc = cc ^ (row & 7);
    ag[j] = Ab + (size_t)row * K + gc * 8;
    bg[j] = Bb + (size_t)row * K + gc * 8;
    al[j] = &As[ci * 8];
    bl[j] = &Bs[ci * 8];
  }

  const int lane = tid & 63, wid = tid >> 6;
  const int wm = (wid >> 1) * 64, wn = (wid & 1) * 64;
  const int q = lane >> 4, r = lane & 15;

  floatx4 zero = {0.f, 0.f, 0.f, 0.f};
  floatx4 acc[4][4];
#pragma unroll
  for (int mt = 0; mt < 4; ++mt)
#pragma unroll
    for (int nt = 0; nt < 4; ++nt) acc[mt][nt] = zero;

  int aoff[2][4], boff[2][4];
#pragma unroll
  for (int ks = 0; ks < 2; ++ks)
#pragma unroll
    for (int t = 0; t < 4; ++t) {
      int ra = wm + t * 16 + r;
      aoff[ks][t] = ra * 64 + (((ks * 4 + q) ^ (ra & 7)) * 8);
      int rb = wn + t * 16 + r;
      boff[ks][t] = rb * 64 + (((ks * 4 + q) ^ (rb & 7)) * 8);
    }

  for (int k0 = 0; k0 < K; k0 += 64) {
#pragma unroll
    for (int j = 0; j < 4; ++j) { gll16(ag[j], al[j]); ag[j] += 64; }
#pragma unroll
    for (int j = 0; j < 4; ++j) { gll16(bg[j], bl[j]); bg[j] += 64; }
    __syncthreads();
#pragma unroll
    for (int ks = 0; ks < 2; ++ks) {
      bhalf8 af[4], bf[4];
#pragma unroll
      for (int t = 0; t < 4; ++t) af[t] = *(const bhalf8*)&As[aoff[ks][t]];
#pragma unroll
      for (int t = 0; t < 4; ++t) bf[t] = *(const bhalf8*)&Bs[boff[ks][t]];
#pragma unroll
      for (int mt = 0; mt < 4; ++mt)
#pragma unroll
        for (int nt = 0; nt < 4; ++nt)
          acc[mt][nt] = __builtin_amdgcn_mfma_f32_16x16x32_bf16(af[mt], bf[nt], acc[mt][nt], 0, 0, 0);
    }
    __syncthreads();
  }

  const float* bp = bias + (size_t)step * sBias;
  if (flags & 2) {
    float* C = (float*)Cv;
#pragma unroll
    for (int nt = 0; nt < 4; ++nt) {
      int col = n0 + wn + nt * 16 + r;
      float bv = bp[col];
#pragma unroll
      for (int mt = 0; mt < 4; ++mt)
#pragma unroll
        for (int rr = 0; rr < 4; ++rr) {
          size_t row = row0 + wm + mt * 16 + q * 4 + rr;
          C[row * (size_t)N + col] = acc[mt][nt][rr] + bv;
        }
    }
  } else {
    u16* C = (u16*)Cv;
    float sA[4], qA[4];
#pragma unroll
    for (int nt = 0; nt < 4; ++nt) { sA[nt] = 0.f; qA[nt] = 0.f; }
#pragma unroll
    for (int nt = 0; nt < 4; ++nt) {
      int col = n0 + wn + nt * 16 + r;
      float bv = bp[col];
#pragma unroll
      for (int mt = 0; mt < 4; ++mt)
#pragma unroll
        for (int rr = 0; rr < 4; ++rr) {
          size_t row = row0 + wm + mt * 16 + q * 4 + rr;
          u16 hb = f2b(tanh_fast(acc[mt][nt][rr] + bv));
          C[row * (size_t)N + col] = hb;
          if (flags & 4) {
            float vf = b2f(hb);          // stats on the bf16-rounded stored value
            sA[nt] += vf; qA[nt] += vf * vf;
          }
        }
    }
    if (flags & 4) {
      // reduce over the 4 q-subgroups (this wave's 64 rows); no barrier needed
#pragma unroll
      for (int nt = 0; nt < 4; ++nt) {
        sA[nt] += __shfl_xor(sA[nt], 16); qA[nt] += __shfl_xor(qA[nt], 16);
        sA[nt] += __shfl_xor(sA[nt], 32); qA[nt] += __shfl_xor(qA[nt], 32);
      }
      if (q == 0) {
        const int G = gridDim.z;
        const int part = mb * 2 + (wid >> 1);   // 0..63 per step
#pragma unroll
        for (int nt = 0; nt < 4; ++nt) {
          size_t o = ((size_t)part * G + step) * (size_t)N + n0 + wn + nt * 16 + r;
          ps[o] = sA[nt];
          pq[o] = qA[nt];
        }
      }
    }
  }
}

// ----------------- dW transpose: [4096][128][64] -> [64][4096][128] ------------------
__global__ void trans_dW(const float* __restrict__ dW, float* __restrict__ dWt) {
  __shared__ float L[128 * 65];
  int b = blockIdx.x, tid = threadIdx.x;
  const float* src = dW + (size_t)b * 8192;
  for (int j = tid; j < 8192; j += 256) { int d = j >> 6, i = j & 63; L[d * 65 + i] = src[j]; }
  __syncthreads();
  for (int it = 0; it < 32; ++it) {
    int i = it * 2 + (tid >> 7), d = tid & 127;
    dWt[((size_t)i * 4096 + b) * 128 + d] = L[d * 65 + i];
  }
}

// ----------------- driver dots: vol[i][b], zz[i][b] (wave per task) ------------------
__global__ void driver_k(const float* __restrict__ Z, const float* __restrict__ dWt,
                         float* __restrict__ vol, float* __restrict__ zz) {
  int task = blockIdx.x * 4 + (threadIdx.x >> 6);
  int lane = threadIdx.x & 63;
  int b = task >> 6, i = task & 63;
  const float2* zp = (const float2*)(Z + ((size_t)i * 4096 + b) * 128) + lane;
  const float2* wp = (const float2*)(dWt + ((size_t)i * 4096 + b) * 128) + lane;
  float2 z = *zp, w = *wp;
  float pv = z.x * w.x + z.y * w.y;
  float pz = 0.f;
  if (i >= 17) {
    const float2* zd = (const float2*)(Z + ((size_t)(i - 17) * 4096 + b) * 128) + lane;
    float2 d = *zd;
    pz = z.x * d.x + z.y * d.y;
  }
#pragma unroll
  for (int off = 32; off > 0; off >>= 1) {
    pv += __shfl_xor(pv, off);
    pz += __shfl_xor(pz, off);
  }
  if (lane == 0) {
    vol[(size_t)i * 4096 + b] = pv;
    zz[(size_t)i * 4096 + b] = pz;
  }
}

// ---------- fallback driver reading dW_f directly (no 128 MB transpose buf) ----------
__global__ void driver_slow(const float* __restrict__ Z, const float* __restrict__ dW,
                            float* __restrict__ vol, float* __restrict__ zz) {
  int task = blockIdx.x * 4 + (threadIdx.x >> 6);
  int lane = threadIdx.x & 63;
  int b = task >> 6, i = task & 63;
  const float* zp = Z + ((size_t)i * 4096 + b) * 128;
  float z0 = zp[lane], z1 = zp[lane + 64];
  float w0 = dW[(size_t)b * 8192 + (size_t)lane * 64 + i];
  float w1 = dW[(size_t)b * 8192 + (size_t)(lane + 64) * 64 + i];
  float pv = z0 * w0 + z1 * w1;
  float pz = 0.f;
  if (i >= 17) {
    const float* zd = Z + ((size_t)(i - 17) * 4096 + b) * 128;
    pz = z0 * zd[lane] + z1 * zd[lane + 64];
  }
#pragma unroll
  for (int off = 32; off > 0; off >>= 1) {
    pv += __shfl_xor(pv, off);
    pz += __shfl_xor(pz, off);
  }
  if (lane == 0) {
    vol[(size_t)i * 4096 + b] = pv;
    zz[(size_t)i * 4096 + b] = pz;
  }
}

// ----------------- sequential scan (one thread per batch element) --------------------
__global__ void scan_k(const float* __restrict__ vol, const float* __restrict__ zz,
                       const float* __restrict__ xs, const float* __restrict__ y0p,
                       float* __restrict__ out) {
  int b = blockIdx.x * 256 + threadIdx.x;
  float y0 = y0p[0];
  float* yt_out = out;                     // [4096]
  float* y_out = out + 4096;               // [4096][81]
  float yhist[64];
  float y_t = y0;
#pragma unroll
  for (int i = 0; i < 64; ++i) {
    float yd = y0;
    if (i >= 17) yd = yhist[i - 17];
    float drv = -y_t + 0.1f * yd + zz[(size_t)i * 4096 + b] + xs[(size_t)i * 4096 + b];
    y_t = y_t - drv * 0.02f + vol[(size_t)i * 4096 + b];
    yhist[i] = y_t;
    y_out[(size_t)b * 81 + i + 17] = y_t;
  }
  for (int t = 0; t < 17; ++t) y_out[(size_t)b * 81 + t] = y0;
  yt_out[b] = y_t;
}

// ----------------- z output: [64][4096][128] -> out z [4096][128][81] ----------------
__global__ void zout_k(const float* __restrict__ Z, float* __restrict__ outz) {
  __shared__ float L[128 * 65];
  int b = blockIdx.x, tid = threadIdx.x;
  for (int j = tid; j < 8192; j += 256) {
    int i = j >> 7, d = j & 127;
    L[d * 65 + i] = Z[((size_t)i * 4096 + b) * 128 + d];
  }
  __syncthreads();
  float* dst = outz + (size_t)b * 10368;
  for (int j = tid; j < 10368; j += 256) {
    int d = j / 81, t = j % 81;
    dst[j] = (t < 17) ? 0.f : L[d * 65 + (t - 17)];
  }
}

extern "C" void kernel_launch(void* const* d_in, const int* in_sizes, int n_in,
                              void* d_out, int out_size, void* d_ws, size_t ws_size,
                              hipStream_t stream) {
  const float* x     = (const float*)d_in[0];   // [4096][128][81]
  const float* dWf   = (const float*)d_in[1];   // [4096][128][1][64]
  const float* y0p   = (const float*)d_in[2];   // [1][1]
  const float* bing  = (const float*)d_in[3];   // [257]
  const float* binb  = (const float*)d_in[4];
  const float* W_in  = (const float*)d_in[5];   // [257][1024]
  const float* b_in  = (const float*)d_in[6];
  const float* Ws_h  = (const float*)d_in[7];   // [3][1024][1024]
  const float* bs_h  = (const float*)d_in[8];
  const float* bns_g = (const float*)d_in[9];
  const float* bns_b = (const float*)d_in[10];
  const float* bog   = (const float*)d_in[11];
  const float* bob   = (const float*)d_in[12];
  const float* W_out = (const float*)d_in[13];  // [1024][128]
  const float* b_out = (const float*)d_in[14];
  float* out = (float*)d_out;

  // ---- adaptive chunk size so total ws usage fits ws_size ----
  const size_t DWTB = 134217728ull;  // 64*4096*128*4  (dWt transpose buffer)
  const size_t PERSIST = 141000000ull;  // Z(128MB)+xs/vol/zz+stats+Wt_i, w/ margin
  auto chunkB = [](int G) { return (size_t)G * 19673088ull + 262144ull; };
  int G = 16;
  while (G > 1) {
    size_t cb = chunkB(G); if (cb < DWTB) cb = DWTB;
    if (PERSIST + cb <= ws_size) break;
    G >>= 1;
  }
  size_t needFast = chunkB(G) < DWTB ? DWTB : chunkB(G);
  bool fast_dw = (PERSIST + needFast) <= ws_size;

  char* w = (char*)d_ws;
  auto alloc = [&](size_t bytes) { char* p = w; w += (bytes + 255) & ~(size_t)255; return p; };
  // persistent region
  float* Z     = (float*)alloc(64ull * 4096 * 128 * 4);  // 128 MB
  float* xs    = (float*)alloc(64ull * 4096 * 4);
  float* volb  = (float*)alloc(64ull * 4096 * 4);
  float* zzb   = (float*)alloc(64ull * 4096 * 4);
  float* meanx = (float*)alloc(10240 * 4);
  float* rstdx = (float*)alloc(10240 * 4);
  float* psx   = (float*)alloc(16ull * 10240 * 4);
  float* pqx   = (float*)alloc(16ull * 10240 * 4);
  u16*   Wt_i  = (u16*)alloc(1024ull * 320 * 2);
  // chunk region (re-used by dWt after the chunk loop finishes)
  char*  cbase = w;
  u16*   S_a   = (u16*)alloc((size_t)G * 4096 * 1024 * 2);
  u16*   S_b   = (u16*)alloc((size_t)G * 4096 * 1024 * 2);
  u16*   Wt_h  = (u16*)alloc((size_t)G * 1024 * 1024 * 2);
  u16*   Wt_o  = (u16*)alloc((size_t)G * 128 * 1024 * 2);
  float* psum  = (float*)alloc(64ull * G * 1024 * 4);
  float* pqsum = (float*)alloc(64ull * G * 1024 * 4);
  float* a_buf = (float*)alloc((size_t)G * 1024 * 4);
  float* c_buf = (float*)alloc((size_t)G * 1024 * 4);
  float* bias2 = (float*)alloc((size_t)G * 1024 * 4);
  u16*   INPT  = S_b;              // dead once the input GEMM writes S_a
  float* dWt   = (float*)cbase;    // valid only after all chunks complete

  // once: input-BN stats + W_in transpose
  xstats_partial<<<dim3(40, 16), 256, 0, stream>>>(x, psx, pqx);
  xstats_final<<<40, 256, 0, stream>>>(psx, pqx, meanx, rstdx);
  transpose_win<<<1280, 256, 0, stream>>>(W_in, Wt_i);

  for (int c0 = 0; c0 < 64; c0 += G) {
    build_inpt<<<4096, 256, 0, stream>>>(x, meanx, rstdx, bing, binb, INPT, xs, c0, G);
    // input GEMM, fused stats for layer-0 BN
    gemm_bt<<<dim3(8, 32, G), 256, 0, stream>>>(INPT, Wt_i, b_in, S_a, 320, 1024, 0, 0, 1 | 4, psum, pqsum);
    u16* bufs[2] = {S_a, S_b};
    for (int l = 0; l < 3; ++l) {
      u16* Sin = bufs[l & 1];
      u16* Sout = bufs[(l + 1) & 1];
      const float* Wl = Ws_h + (size_t)l * 1024 * 1024;
      stats_final_S<<<4 * G, 256, 0, stream>>>(psum, pqsum, bns_g + l * 1024, bns_b + l * 1024, a_buf, c_buf, G * 1024);
      scaleW<<<dim3(16, 16), 256, 0, stream>>>(Wl, a_buf, Wt_h, 1024, G);
      biasfold<<<dim3(4, G), 256, 0, stream>>>(Wl, c_buf, bs_h + l * 1024, bias2, 1024);
      // hidden GEMM, fused stats for next BN (layer l+1 or bn_out)
      gemm_bt<<<dim3(8, 32, G), 256, 0, stream>>>(Sin, Wt_h, bias2, Sout, 1024, 1024, 1024ll * 1024, 1024, 1 | 4, psum, pqsum);
    }
    // output layer (bn_out folded), fp32 Z for this chunk
    stats_final_S<<<4 * G, 256, 0, stream>>>(psum, pqsum, bog, bob, a_buf, c_buf, G * 1024);
    scaleW<<<dim3(2, 16), 256, 0, stream>>>(W_out, a_buf, Wt_o, 128, G);
    biasfold<<<dim3(1, G), 128, 0, stream>>>(W_out, c_buf, b_out, bias2, 128);
    gemm_bt<<<dim3(1, 32, G), 256, 0, stream>>>(S_b, Wt_o, bias2, Z + (size_t)c0 * 4096 * 128, 1024, 128, 128ll * 1024, 128, 2, psum, pqsum);
  }

  // finish: driver dots, scan, outputs
  if (fast_dw) {
    trans_dW<<<4096, 256, 0, stream>>>(dWf, dWt);
    driver_k<<<65536, 256, 0, stream>>>(Z, dWt, volb, zzb);
  } else {
    driver_slow<<<65536, 256, 0, stream>>>(Z, dWf, volb, zzb);
  }
  scan_k<<<16, 256, 0, stream>>>(volb, zzb, xs, y0p, out);
  zout_k<<<4096, 256, 0, stream>>>(Z, out + 4096 + 4096 * 81);
}

// Round 5
// 4935.017 us; speedup vs baseline: 1.0920x; 1.0920x over previous
//
#include <hip/hip_runtime.h>

typedef unsigned short u16;
typedef short bhalf8 __attribute__((ext_vector_type(8)));
typedef float floatx4 __attribute__((ext_vector_type(4)));

// B=4096, DX=128, DD=128, N=64, ND=16, T=81, DH=1024, L=3, DT=0.02, EPS=1e-5

__device__ __forceinline__ float b2f(u16 h) {
  unsigned int u = ((unsigned int)h) << 16; float f; __builtin_memcpy(&f, &u, 4); return f;
}
__device__ __forceinline__ u16 f2b(float f) {
  unsigned int u; __builtin_memcpy(&u, &f, 4);
  u = u + 0x7fffu + ((u >> 16) & 1u);           // RNE bf16
  return (u16)(u >> 16);
}
__device__ __forceinline__ float tanh_fast(float x) {
  float cx = fminf(fmaxf(x, -15.f), 15.f);
  float e = __expf(2.f * cx);
  return __fdividef(e - 1.f, e + 1.f);
}
__device__ __forceinline__ void gll16(const void* g, void* l) {
  __builtin_amdgcn_global_load_lds(
      (const __attribute__((address_space(1))) unsigned int*)g,
      (__attribute__((address_space(3))) unsigned int*)l, 16, 0, 0);
}

// ---------------- x stats: per (d, t) column over batch, t in [0,80) ----------------
__global__ void xstats_partial(const float* __restrict__ x, float* __restrict__ ps, float* __restrict__ pq) {
  int p = blockIdx.x * 256 + threadIdx.x;      // 0..10239  (d*80+t)
  int bc = blockIdx.y;                          // 0..15
  int d = p / 80, t = p % 80;
  const float* xp = x + (size_t)d * 81 + t;
  float s = 0.f, q = 0.f;
  int b0 = bc * 256;
  for (int b = b0; b < b0 + 256; ++b) {
    float v = xp[(size_t)b * 10368];
    s += v; q += v * v;
  }
  ps[(size_t)bc * 10240 + p] = s;
  pq[(size_t)bc * 10240 + p] = q;
}

__global__ void xstats_final(const float* __restrict__ ps, const float* __restrict__ pq,
                             float* __restrict__ meanx, float* __restrict__ rstdx) {
  int p = blockIdx.x * 256 + threadIdx.x;
  float s = 0.f, q = 0.f;
  for (int c = 0; c < 16; ++c) { s += ps[(size_t)c * 10240 + p]; q += pq[(size_t)c * 10240 + p]; }
  float m = s * (1.0f / 4096.0f);
  float v = q * (1.0f / 4096.0f) - m * m;
  meanx[p] = m;
  rstdx[p] = rsqrtf(v + 1e-5f);
}

// ------- build normalized input [G][4096][320] bf16 for steps c0..c0+G-1, + xs -------
__global__ void build_inpt(const float* __restrict__ x, const float* __restrict__ meanx,
                           const float* __restrict__ rstdx, const float* __restrict__ g,
                           const float* __restrict__ bb, u16* __restrict__ inpt,
                           float* __restrict__ xs, int c0, int G) {
  __shared__ float xl[128 * 33];                // window <=32 cols, padded stride 33
  int b = blockIdx.x, tid = threadIdx.x;
  int W = G + 16;                               // columns needed: [c0, c0+G+16)
  const float* xb = x + (size_t)b * 10368;
  for (int j = tid; j < 128 * W; j += 256) {
    int d = j / W, t = j % W;
    xl[d * 33 + t] = xb[(size_t)d * 81 + c0 + t];
  }
  __syncthreads();
  int lane = tid & 63, wid = tid >> 6;
  for (int i = wid; i < G; i += 4) {
    float s = xl[lane * 33 + i + 16] + xl[(lane + 64) * 33 + i + 16];
#pragma unroll
    for (int off = 32; off > 0; off >>= 1) s += __shfl_xor(s, off);
    if (lane == 0) xs[(size_t)(c0 + i) * 4096 + b] = 0.01f * s;
  }
  for (int i = 0; i < G; ++i) {
    u16* row = inpt + ((size_t)i * 4096 + b) * 320;
    int tt = c0 + i + 16, td = c0 + i;
    for (int col = tid; col < 320; col += 256) {
      float val;
      if (col < 128) {
        int d = col;
        val = (xl[d * 33 + i + 16] - meanx[d * 80 + tt]) * rstdx[d * 80 + tt] * g[col] + bb[col];
      } else if (col < 256) {
        int d = col - 128;
        val = (xl[d * 33 + i] - meanx[d * 80 + td]) * rstdx[d * 80 + td] * g[col] + bb[col];
      } else if (col == 256) {
        val = bb[256];           // constant column: (x-mean)=0 -> bias only
      } else {
        val = 0.f;               // K padding 257->320
      }
      row[col] = f2b(val);
    }
  }
}

// --------------- W_in transpose to [1024][320] bf16 (zero-padded K) ------------------
__global__ void transpose_win(const float* __restrict__ W, u16* __restrict__ Wt) {
  int id = blockIdx.x * 256 + threadIdx.x;      // over 1024*320
  int n = id / 320, k = id % 320;
  float v = (k < 257) ? W[(size_t)k * 1024 + n] : 0.f;
  Wt[id] = f2b(v);
}

// ------ stats final: sum 64 per-64-row partials -> a (scale), c (shift) --------------
__global__ void stats_final_S(const float* __restrict__ ps, const float* __restrict__ pq,
                              const float* __restrict__ g, const float* __restrict__ bb,
                              float* __restrict__ a_buf, float* __restrict__ c_buf, int GK) {
  int id = blockIdx.x * 256 + threadIdx.x;      // over G*1024
  int col = id & 1023;
  float s = 0.f, q = 0.f;
  for (int rc = 0; rc < 64; ++rc) { s += ps[(size_t)rc * GK + id]; q += pq[(size_t)rc * GK + id]; }
  float m = s * (1.0f / 4096.0f);
  float v = q * (1.0f / 4096.0f) - m * m;
  float a = g[col] * rsqrtf(v + 1e-5f);
  a_buf[id] = a;
  c_buf[id] = bb[col] - m * a;
}

// --------- W' materialization: Wt[s][n][k] = a[s][k] * W[k][n], bf16, K=1024 ---------
__global__ void scaleW(const float* __restrict__ W, const float* __restrict__ a_buf,
                       u16* __restrict__ Wt, int N, int G) {
  __shared__ float T[64][65];
  __shared__ float aa[64];
  int n0 = blockIdx.x * 64, k0 = blockIdx.y * 64;
  int tid = threadIdx.x;
  int tn = tid & 63, t4 = tid >> 6;
  for (int it = 0; it < 16; ++it) {
    int k = it * 4 + t4;
    T[tn][k] = W[(size_t)(k0 + k) * N + n0 + tn];
  }
  __syncthreads();
  int wk = tid & 63, w4 = tid >> 6;
  for (int s = 0; s < G; ++s) {
    if (tid < 64) aa[tid] = a_buf[(size_t)s * 1024 + k0 + tid];
    __syncthreads();
    u16* out = Wt + ((size_t)s * N + n0) * 1024 + k0;
    for (int it = 0; it < 16; ++it) {
      int n = it * 4 + w4;
      out[(size_t)n * 1024 + wk] = f2b(T[n][wk] * aa[wk]);
    }
    __syncthreads();
  }
}

// --------- bias fold: bias2[s][n] = b0[n] + sum_k c[s][k]*W[k][n] --------------------
__global__ void biasfold(const float* __restrict__ W, const float* __restrict__ c_buf,
                         const float* __restrict__ b0, float* __restrict__ bias2, int N) {
  __shared__ float cl[1024];
  int s = blockIdx.y;
  int n = blockIdx.x * blockDim.x + threadIdx.x;
  for (int j = threadIdx.x; j < 1024; j += blockDim.x) cl[j] = c_buf[(size_t)s * 1024 + j];
  __syncthreads();
  if (n < N) {
    float acc = b0[n];
#pragma unroll 4
    for (int k = 0; k < 1024; ++k) acc += cl[k] * W[(size_t)k * N + n];
    bias2[(size_t)s * N + n] = acc;
  }
}

// ----------------------------- the GEMM (m97-style) ----------------------------------
// A: [G*4096][K] bf16.  Bt: per-(local)step [N][K] bf16 (pre-transposed/scaled).
// C: [G*4096][N];  flags: 1 = tanh + bf16 out, 2 = f32 out (no tanh),
//                  4 = fuse column stats (sum, sum-sq over rows) into ps/pq partials.
// bf16 epilogue: per-wave LDS transpose (reusing the staging pool after the final
// K-loop barrier; wave-private 64x72 tile, DS ops are in-order per wave so no
// barrier) -> 8 ds_read_b128 + 8 global_store_dwordx4 per wave (full 64B lines)
// instead of 64 scattered 2B stores per thread. Stats accumulate on the read-back
// dwords (exact stored bf16), then 3x shfl_xor reduce, lanes<8 store partials.
// XCD-aware bijective block swizzle (T1): consecutive work-ids (which share A/B
// panels) land on the SAME XCD so the per-XCD 4MB L2 captures panel reuse.
__global__ __launch_bounds__(256, 2)
void gemm_bt(const u16* __restrict__ A, const u16* __restrict__ Bt,
             const float* __restrict__ bias, void* __restrict__ Cv,
             int K, int N, long long sB, int sBias, int flags,
             float* __restrict__ ps, float* __restrict__ pq) {
  __shared__ alignas(16) u16 pool[18432];   // 36.9KB: As(16K)+Bs(16K) / 4x 64x72 tiles
  u16* As = pool;
  u16* Bs = pool + 8192;
  const int tid = threadIdx.x;

  // ---- bijective XCD swizzle over the full 3D grid (x fastest in work-id) ----
  const int gx = gridDim.x;
  const int gxy = gx * gridDim.y;
  const int nwg = gxy * gridDim.z;
  const int orig = blockIdx.z * gxy + blockIdx.y * gx + blockIdx.x;
  const int qq = nwg >> 3, r8 = nwg & 7;
  const int xcd = orig & 7, off8 = orig >> 3;
  const int wg = (xcd < r8 ? xcd * (qq + 1) : r8 * (qq + 1) + (xcd - r8) * qq) + off8;
  const int step = wg / gxy;
  const int wrem = wg - step * gxy;
  const int mb = wrem / gx;
  const int m0 = mb * 128;
  const int n0 = (wrem % gx) * 128;

  const size_t row0 = (size_t)step * 4096 + m0;
  const u16* Ab = A + row0 * (size_t)K;
  const u16* Bb = Bt + (size_t)step * (size_t)sB + (size_t)n0 * (size_t)K;

  // staging pointers (16B chunks; xor-swizzle chunks within each 128B row)
  const u16* ag[4]; const u16* bg[4]; u16* al[4]; u16* bl[4];
#pragma unroll
  for (int j = 0; j < 4; ++j) {
    int ci = j * 256 + tid;
    int row = ci >> 3, cc = ci & 7;
    int gc = cc ^ (row & 7);
    ag[j] = Ab + (size_t)row * K + gc * 8;
    bg[j] = Bb + (size_t)row * K + gc * 8;
    al[j] = &As[ci * 8];
    bl[j] = &Bs[ci * 8];
  }

  const int lane = tid & 63, wid = tid >> 6;
  const int wm = (wid >> 1) * 64, wn = (wid & 1) * 64;
  const int q = lane >> 4, r = lane & 15;

  floatx4 zero = {0.f, 0.f, 0.f, 0.f};
  floatx4 acc[4][4];
#pragma unroll
  for (int mt = 0; mt < 4; ++mt)
#pragma unroll
    for (int nt = 0; nt < 4; ++nt) acc[mt][nt] = zero;

  int aoff[2][4], boff[2][4];
#pragma unroll
  for (int ks = 0; ks < 2; ++ks)
#pragma unroll
    for (int t = 0; t < 4; ++t) {
      int ra = wm + t * 16 + r;
      aoff[ks][t] = ra * 64 + (((ks * 4 + q) ^ (ra & 7)) * 8);
      int rb = wn + t * 16 + r;
      boff[ks][t] = rb * 64 + (((ks * 4 + q) ^ (rb & 7)) * 8);
    }

  for (int k0 = 0; k0 < K; k0 += 64) {
#pragma unroll
    for (int j = 0; j < 4; ++j) { gll16(ag[j], al[j]); ag[j] += 64; }
#pragma unroll
    for (int j = 0; j < 4; ++j) { gll16(bg[j], bl[j]); bg[j] += 64; }
    __syncthreads();
#pragma unroll
    for (int ks = 0; ks < 2; ++ks) {
      bhalf8 af[4], bf[4];
#pragma unroll
      for (int t = 0; t < 4; ++t) af[t] = *(const bhalf8*)&As[aoff[ks][t]];
#pragma unroll
      for (int t = 0; t < 4; ++t) bf[t] = *(const bhalf8*)&Bs[boff[ks][t]];
#pragma unroll
      for (int mt = 0; mt < 4; ++mt)
#pragma unroll
        for (int nt = 0; nt < 4; ++nt)
          acc[mt][nt] = __builtin_amdgcn_mfma_f32_16x16x32_bf16(af[mt], bf[nt], acc[mt][nt], 0, 0, 0);
    }
    __syncthreads();
  }
  // after this barrier As/Bs are dead in all waves -> pool reusable per-wave

  const float* bp = bias + (size_t)step * sBias;
  if (flags & 2) {
    float* C = (float*)Cv;
#pragma unroll
    for (int nt = 0; nt < 4; ++nt) {
      int col = n0 + wn + nt * 16 + r;
      float bv = bp[col];
#pragma unroll
      for (int mt = 0; mt < 4; ++mt)
#pragma unroll
        for (int rr = 0; rr < 4; ++rr) {
          size_t row = row0 + wm + mt * 16 + q * 4 + rr;
          C[row * (size_t)N + col] = acc[mt][nt][rr] + bv;
        }
    }
  } else {
    u16* C = (u16*)Cv;
    u16* Tw = pool + wid * 4608;   // wave-private 64 rows x 72 u16 (9216B)
    // transpose-in: 64 ds_write_b16 per lane-position (pad-72 rows)
#pragma unroll
    for (int nt = 0; nt < 4; ++nt) {
      float bv = bp[n0 + wn + nt * 16 + r];
#pragma unroll
      for (int mt = 0; mt < 4; ++mt)
#pragma unroll
        for (int rr = 0; rr < 4; ++rr)
          Tw[(mt * 16 + q * 4 + rr) * 72 + nt * 16 + r] = f2b(tanh_fast(acc[mt][nt][rr] + bv));
    }
    // read back row-major (wave-private; DS in-order, no barrier) + coalesced store
    const int hh = lane >> 3, cg = lane & 7;
    float s8[8], q8[8];
#pragma unroll
    for (int k = 0; k < 8; ++k) { s8[k] = 0.f; q8[k] = 0.f; }
#pragma unroll
    for (int p = 0; p < 8; ++p) {
      int y = p * 8 + hh;
      uint4 v = *(const uint4*)&Tw[y * 72 + cg * 8];
      *(uint4*)&C[(row0 + wm + y) * (size_t)N + n0 + wn + cg * 8] = v;
      if (flags & 4) {
        unsigned int uu[4] = {v.x, v.y, v.z, v.w};
#pragma unroll
        for (int d = 0; d < 4; ++d) {
          float lo = b2f((u16)(uu[d] & 0xffff));
          float hi = b2f((u16)(uu[d] >> 16));
          s8[d * 2]     += lo; q8[d * 2]     += lo * lo;
          s8[d * 2 + 1] += hi; q8[d * 2 + 1] += hi * hi;
        }
      }
    }
    if (flags & 4) {
#pragma unroll
      for (int k = 0; k < 8; ++k) {
        s8[k] += __shfl_xor(s8[k], 8);  q8[k] += __shfl_xor(q8[k], 8);
        s8[k] += __shfl_xor(s8[k], 16); q8[k] += __shfl_xor(q8[k], 16);
        s8[k] += __shfl_xor(s8[k], 32); q8[k] += __shfl_xor(q8[k], 32);
      }
      if (hh == 0) {
        const int Gz = gridDim.z;
        const int part = mb * 2 + (wid >> 1);   // 0..63 per step (64-row groups)
        size_t o = ((size_t)part * Gz + step) * (size_t)N + n0 + wn + cg * 8;
#pragma unroll
        for (int k = 0; k < 8; ++k) { ps[o + k] = s8[k]; pq[o + k] = q8[k]; }
      }
    }
  }
}

// ----------------- dW transpose: [4096][128][64] -> [64][4096][128] ------------------
__global__ void trans_dW(const float* __restrict__ dW, float* __restrict__ dWt) {
  __shared__ float L[128 * 65];
  int b = blockIdx.x, tid = threadIdx.x;
  const float* src = dW + (size_t)b * 8192;
  for (int j = tid; j < 8192; j += 256) { int d = j >> 6, i = j & 63; L[d * 65 + i] = src[j]; }
  __syncthreads();
  for (int it = 0; it < 32; ++it) {
    int i = it * 2 + (tid >> 7), d = tid & 127;
    dWt[((size_t)i * 4096 + b) * 128 + d] = L[d * 65 + i];
  }
}

// ----------------- driver dots: vol[i][b], zz[i][b] (wave per task) ------------------
__global__ void driver_k(const float* __restrict__ Z, const float* __restrict__ dWt,
                         float* __restrict__ vol, float* __restrict__ zz) {
  int task = blockIdx.x * 4 + (threadIdx.x >> 6);
  int lane = threadIdx.x & 63;
  int b = task >> 6, i = task & 63;
  const float2* zp = (const float2*)(Z + ((size_t)i * 4096 + b) * 128) + lane;
  const float2* wp = (const float2*)(dWt + ((size_t)i * 4096 + b) * 128) + lane;
  float2 z = *zp, w = *wp;
  float pv = z.x * w.x + z.y * w.y;
  float pz = 0.f;
  if (i >= 17) {
    const float2* zd = (const float2*)(Z + ((size_t)(i - 17) * 4096 + b) * 128) + lane;
    float2 d = *zd;
    pz = z.x * d.x + z.y * d.y;
  }
#pragma unroll
  for (int off = 32; off > 0; off >>= 1) {
    pv += __shfl_xor(pv, off);
    pz += __shfl_xor(pz, off);
  }
  if (lane == 0) {
    vol[(size_t)i * 4096 + b] = pv;
    zz[(size_t)i * 4096 + b] = pz;
  }
}

// ---------- fallback driver reading dW_f directly (no 128 MB transpose buf) ----------
__global__ void driver_slow(const float* __restrict__ Z, const float* __restrict__ dW,
                            float* __restrict__ vol, float* __restrict__ zz) {
  int task = blockIdx.x * 4 + (threadIdx.x >> 6);
  int lane = threadIdx.x & 63;
  int b = task >> 6, i = task & 63;
  const float* zp = Z + ((size_t)i * 4096 + b) * 128;
  float z0 = zp[lane], z1 = zp[lane + 64];
  float w0 = dW[(size_t)b * 8192 + (size_t)lane * 64 + i];
  float w1 = dW[(size_t)b * 8192 + (size_t)(lane + 64) * 64 + i];
  float pv = z0 * w0 + z1 * w1;
  float pz = 0.f;
  if (i >= 17) {
    const float* zd = Z + ((size_t)(i - 17) * 4096 + b) * 128;
    pz = z0 * zd[lane] + z1 * zd[lane + 64];
  }
#pragma unroll
  for (int off = 32; off > 0; off >>= 1) {
    pv += __shfl_xor(pv, off);
    pz += __shfl_xor(pz, off);
  }
  if (lane == 0) {
    vol[(size_t)i * 4096 + b] = pv;
    zz[(size_t)i * 4096 + b] = pz;
  }
}

// ----------------- sequential scan (one thread per batch element) --------------------
__global__ void scan_k(const float* __restrict__ vol, const float* __restrict__ zz,
                       const float* __restrict__ xs, const float* __restrict__ y0p,
                       float* __restrict__ out) {
  int b = blockIdx.x * 256 + threadIdx.x;
  float y0 = y0p[0];
  float* yt_out = out;                     // [4096]
  float* y_out = out + 4096;               // [4096][81]
  float yhist[64];
  float y_t = y0;
#pragma unroll
  for (int i = 0; i < 64; ++i) {
    float yd = y0;
    if (i >= 17) yd = yhist[i - 17];
    float drv = -y_t + 0.1f * yd + zz[(size_t)i * 4096 + b] + xs[(size_t)i * 4096 + b];
    y_t = y_t - drv * 0.02f + vol[(size_t)i * 4096 + b];
    yhist[i] = y_t;
    y_out[(size_t)b * 81 + i + 17] = y_t;
  }
  for (int t = 0; t < 17; ++t) y_out[(size_t)b * 81 + t] = y0;
  yt_out[b] = y_t;
}

// ----------------- z output: [64][4096][128] -> out z [4096][128][81] ----------------
__global__ void zout_k(const float* __restrict__ Z, float* __restrict__ outz) {
  __shared__ float L[128 * 65];
  int b = blockIdx.x, tid = threadIdx.x;
  for (int j = tid; j < 8192; j += 256) {
    int i = j >> 7, d = j & 127;
    L[d * 65 + i] = Z[((size_t)i * 4096 + b) * 128 + d];
  }
  __syncthreads();
  float* dst = outz + (size_t)b * 10368;
  for (int j = tid; j < 10368; j += 256) {
    int d = j / 81, t = j % 81;
    dst[j] = (t < 17) ? 0.f : L[d * 65 + (t - 17)];
  }
}

extern "C" void kernel_launch(void* const* d_in, const int* in_sizes, int n_in,
                              void* d_out, int out_size, void* d_ws, size_t ws_size,
                              hipStream_t stream) {
  const float* x     = (const float*)d_in[0];   // [4096][128][81]
  const float* dWf   = (const float*)d_in[1];   // [4096][128][1][64]
  const float* y0p   = (const float*)d_in[2];   // [1][1]
  const float* bing  = (const float*)d_in[3];   // [257]
  const float* binb  = (const float*)d_in[4];
  const float* W_in  = (const float*)d_in[5];   // [257][1024]
  const float* b_in  = (const float*)d_in[6];
  const float* Ws_h  = (const float*)d_in[7];   // [3][1024][1024]
  const float* bs_h  = (const float*)d_in[8];
  const float* bns_g = (const float*)d_in[9];
  const float* bns_b = (const float*)d_in[10];
  const float* bog   = (const float*)d_in[11];
  const float* bob   = (const float*)d_in[12];
  const float* W_out = (const float*)d_in[13];  // [1024][128]
  const float* b_out = (const float*)d_in[14];
  float* out = (float*)d_out;

  // ---- adaptive chunk size so total ws usage fits ws_size ----
  const size_t DWTB = 134217728ull;  // 64*4096*128*4  (dWt transpose buffer)
  const size_t PERSIST = 141000000ull;  // Z(128MB)+xs/vol/zz+stats+Wt_i, w/ margin
  auto chunkB = [](int G) { return (size_t)G * 19673088ull + 262144ull; };
  int G = 16;
  while (G > 1) {
    size_t cb = chunkB(G); if (cb < DWTB) cb = DWTB;
    if (PERSIST + cb <= ws_size) break;
    G >>= 1;
  }
  size_t needFast = chunkB(G) < DWTB ? DWTB : chunkB(G);
  bool fast_dw = (PERSIST + needFast) <= ws_size;

  char* w = (char*)d_ws;
  auto alloc = [&](size_t bytes) { char* p = w; w += (bytes + 255) & ~(size_t)255; return p; };
  // persistent region
  float* Z     = (float*)alloc(64ull * 4096 * 128 * 4);  // 128 MB
  float* xs    = (float*)alloc(64ull * 4096 * 4);
  float* volb  = (float*)alloc(64ull * 4096 * 4);
  float* zzb   = (float*)alloc(64ull * 4096 * 4);
  float* meanx = (float*)alloc(10240 * 4);
  float* rstdx = (float*)alloc(10240 * 4);
  float* psx   = (float*)alloc(16ull * 10240 * 4);
  float* pqx   = (float*)alloc(16ull * 10240 * 4);
  u16*   Wt_i  = (u16*)alloc(1024ull * 320 * 2);
  // chunk region (re-used by dWt after the chunk loop finishes)
  char*  cbase = w;
  u16*   S_a   = (u16*)alloc((size_t)G * 4096 * 1024 * 2);
  u16*   S_b   = (u16*)alloc((size_t)G * 4096 * 1024 * 2);
  u16*   Wt_h  = (u16*)alloc((size_t)G * 1024 * 1024 * 2);
  u16*   Wt_o  = (u16*)alloc((size_t)G * 128 * 1024 * 2);
  float* psum  = (float*)alloc(64ull * G * 1024 * 4);
  float* pqsum = (float*)alloc(64ull * G * 1024 * 4);
  float* a_buf = (float*)alloc((size_t)G * 1024 * 4);
  float* c_buf = (float*)alloc((size_t)G * 1024 * 4);
  float* bias2 = (float*)alloc((size_t)G * 1024 * 4);
  u16*   INPT  = S_b;              // dead once the input GEMM writes S_a
  float* dWt   = (float*)cbase;    // valid only after all chunks complete

  // once: input-BN stats + W_in transpose
  xstats_partial<<<dim3(40, 16), 256, 0, stream>>>(x, psx, pqx);
  xstats_final<<<40, 256, 0, stream>>>(psx, pqx, meanx, rstdx);
  transpose_win<<<1280, 256, 0, stream>>>(W_in, Wt_i);

  for (int c0 = 0; c0 < 64; c0 += G) {
    build_inpt<<<4096, 256, 0, stream>>>(x, meanx, rstdx, bing, binb, INPT, xs, c0, G);
    // input GEMM, fused stats for layer-0 BN
    gemm_bt<<<dim3(8, 32, G), 256, 0, stream>>>(INPT, Wt_i, b_in, S_a, 320, 1024, 0, 0, 1 | 4, psum, pqsum);
    u16* bufs[2] = {S_a, S_b};
    for (int l = 0; l < 3; ++l) {
      u16* Sin = bufs[l & 1];
      u16* Sout = bufs[(l + 1) & 1];
      const float* Wl = Ws_h + (size_t)l * 1024 * 1024;
      stats_final_S<<<4 * G, 256, 0, stream>>>(psum, pqsum, bns_g + l * 1024, bns_b + l * 1024, a_buf, c_buf, G * 1024);
      scaleW<<<dim3(16, 16), 256, 0, stream>>>(Wl, a_buf, Wt_h, 1024, G);
      biasfold<<<dim3(4, G), 256, 0, stream>>>(Wl, c_buf, bs_h + l * 1024, bias2, 1024);
      // hidden GEMM, fused stats for next BN (layer l+1 or bn_out)
      gemm_bt<<<dim3(8, 32, G), 256, 0, stream>>>(Sin, Wt_h, bias2, Sout, 1024, 1024, 1024ll * 1024, 1024, 1 | 4, psum, pqsum);
    }
    // output layer (bn_out folded), fp32 Z for this chunk
    stats_final_S<<<4 * G, 256, 0, stream>>>(psum, pqsum, bog, bob, a_buf, c_buf, G * 1024);
    scaleW<<<dim3(2, 16), 256, 0, stream>>>(W_out, a_buf, Wt_o, 128, G);
    biasfold<<<dim3(1, G), 128, 0, stream>>>(W_out, c_buf, b_out, bias2, 128);
    gemm_bt<<<dim3(1, 32, G), 256, 0, stream>>>(S_b, Wt_o, bias2, Z + (size_t)c0 * 4096 * 128, 1024, 128, 128ll * 1024, 128, 2, psum, pqsum);
  }

  // finish: driver dots, scan, outputs
  if (fast_dw) {
    trans_dW<<<4096, 256, 0, stream>>>(dWf, dWt);
    driver_k<<<65536, 256, 0, stream>>>(Z, dWt, volb, zzb);
  } else {
    driver_slow<<<65536, 256, 0, stream>>>(Z, dWf, volb, zzb);
  }
  scan_k<<<16, 256, 0, stream>>>(volb, zzb, xs, y0p, out);
  zout_k<<<4096, 256, 0, stream>>>(Z, out + 4096 + 4096 * 81);
}